// Round 7
// baseline (226.706 us; speedup 1.0000x reference)
//
#include <hip/hip_runtime.h>

#define B_ 16
#define D_ 64
#define T_ 4096
#define K_ 512
#define N_ (B_*T_)        // 65536 vectors
#define Q_ (B_*D_*T_)     // 4194304 quantized elements
#define ENC_OFF ((size_t)(2 + Q_))  // encodings start in d_out

// ws layout (bytes) — ~136 KB
#define WS_LOSS    0        // double
#define WS_HIST    16       // int[512]
#define WS_NE      2064     // float[512]
#define WS_CBH     4608     // bf16x8[32*2*64]  (64 KB) codebook hi frags
#define WS_CBL     70144    // bf16x8[32*2*64]  (64 KB) codebook lo frags

typedef __bf16 bf16x8 __attribute__((ext_vector_type(8)));
typedef float  f32x4  __attribute__((ext_vector_type(4)));
typedef float  f32x2  __attribute__((ext_vector_type(2)));

// ---------------- K0: init + ne + codebook hi/lo B-fragments ----------------
// Grid = 16 blocks x 256 threads.
__global__ __launch_bounds__(256) void k0_init(const float* __restrict__ cb,
                                               float* __restrict__ ne,
                                               int* __restrict__ hist,
                                               double* __restrict__ loss,
                                               bf16x8* __restrict__ cbh,
                                               bf16x8* __restrict__ cbl) {
    int bidx = blockIdx.x, tid = threadIdx.x;

    // ne: 32 codes per block, 8 lanes per code
    {
        int code = bidx * 32 + (tid >> 3), sl = tid & 7;
        float s = 0.f;
#pragma unroll
        for (int j = 0; j < 8; ++j) { float c = cb[code * 64 + sl * 8 + j]; s = fmaf(c, c, s); }
        s += __shfl_xor(s, 1); s += __shfl_xor(s, 2); s += __shfl_xor(s, 4);
        if (sl == 0) ne[code] = s;
    }
    if (bidx == 0) {
        hist[tid] = 0; hist[tid + 256] = 0;
        if (tid == 0) *loss = 0.0;
    }

    // B-frag element (ct,ks,lane,j) = cb[ct*16 + (lane&15)][ks*32 + (lane>>4)*8 + j]
    int e = bidx * 256 + tid;
    int ct = e >> 7, ks = (e >> 6) & 1, lane = e & 63;
    int code  = ct * 16 + (lane & 15);
    int dbase = ks * 32 + ((lane >> 4) << 3);
    bf16x8 h, l;
#pragma unroll
    for (int j = 0; j < 8; ++j) {
        float v = cb[code * 64 + dbase + j];
        __bf16 hv = (__bf16)v;
        __bf16 lv = (__bf16)(v - (float)hv);
        h[j] = hv; l[j] = lv;
    }
    cbh[(ct * 2 + ks) * 64 + lane] = h;
    cbl[(ct * 2 + ks) * 64 + lane] = l;
}

// ---------------- K_MAIN: 16-row blocks, grid 4096 = 2 residency rounds -----
// R0-R6 lesson: every per-block lever (atomics, L2 traffic, store policy,
// occupancy) is NULL; R4 counters show ALL pipes <20% busy. Diagnosis:
// grid == resident capacity -> all blocks in lockstep -> stage/MFMA/store
// phases serialize at DEVICE level. Fix: grid 4096 (2x the 8-blocks/CU
// residency) so round-2 blocks start staggered and store phases overlap
// other blocks' compute phases. Also ~2x fewer VMEM instrs per thread
// (16-row tile; ct split 4-way across waves keeps frag traffic flat).
__global__ __launch_bounds__(256, 8) void k_main(const float* __restrict__ in,
                                                 const float* __restrict__ cb,
                                                 const bf16x8* __restrict__ cbh,
                                                 const bf16x8* __restrict__ cbl,
                                                 const float* __restrict__ ne,
                                                 float* __restrict__ out,
                                                 f32x2* __restrict__ enc2,
                                                 int* __restrict__ hist,
                                                 double* __restrict__ loss) {
    __shared__ float X[64][17];      // dim-major: X[d][row], 4.3 KB, 2-way alias max
    __shared__ float ne_s[512];
    __shared__ float smin[4][16];    // per-wave (= per ct-quarter) argmin candidates
    __shared__ int   smid[4][16];
    __shared__ int   sidx[16];
    int tid = threadIdx.x;
    int n0 = blockIdx.x * 16;
    int b  = n0 >> 12, t0 = n0 & (T_ - 1);

    { // stage x-tile: 64 dims x 16 t = 1024 floats; ONE float4 per thread
        int d = tid >> 2, rg = (tid & 3) * 4;
        const float4* ip = (const float4*)(in + ((size_t)b * 64 + d) * T_ + t0 + rg);
        float4 v = ip[0];
        X[d][rg + 0] = v.x; X[d][rg + 1] = v.y; X[d][rg + 2] = v.z; X[d][rg + 3] = v.w;
    }
    ne_s[tid] = ne[tid];
    ne_s[tid + 256] = ne[tid + 256];
    __syncthreads();

    int w = tid >> 6, lane = tid & 63;
    int col = lane & 15, q = lane >> 4;

    // A-frags for the block's 16 rows: A[m=col][k=ks*32+q*8+j] = X[k][col]
    bf16x8 Ah[2], Al[2];
#pragma unroll
    for (int ks = 0; ks < 2; ++ks) {
        bf16x8 h, l;
#pragma unroll
        for (int j = 0; j < 8; ++j) {
            float v = X[ks * 32 + q * 8 + j][col];
            __bf16 hv = (__bf16)v;
            __bf16 lv = (__bf16)(v - (float)hv);
            h[j] = hv; l[j] = lv;
        }
        Ah[ks] = h; Al[ks] = l;
    }

    float m1[4]; int i1[4];
#pragma unroll
    for (int e = 0; e < 4; ++e) { m1[e] = 3.4e38f; i1[e] = 0; }

    // wave w handles codebook tiles ct = w*8 .. w*8+7 (codes w*128..w*128+127)
    for (int c8 = 0; c8 < 8; ++c8) {
        int ct = w * 8 + c8;
        bf16x8 Bh0 = cbh[(ct * 2 + 0) * 64 + lane];
        bf16x8 Bh1 = cbh[(ct * 2 + 1) * 64 + lane];
        bf16x8 Bl0 = cbl[(ct * 2 + 0) * 64 + lane];
        bf16x8 Bl1 = cbl[(ct * 2 + 1) * 64 + lane];
        float nev = ne_s[ct * 16 + col];
        int code = ct * 16 + col;
        f32x4 acc = {0.f, 0.f, 0.f, 0.f};
        acc = __builtin_amdgcn_mfma_f32_16x16x32_bf16(Ah[0], Bh0, acc, 0, 0, 0);
        acc = __builtin_amdgcn_mfma_f32_16x16x32_bf16(Ah[1], Bh1, acc, 0, 0, 0);
        acc = __builtin_amdgcn_mfma_f32_16x16x32_bf16(Ah[0], Bl0, acc, 0, 0, 0);
        acc = __builtin_amdgcn_mfma_f32_16x16x32_bf16(Al[0], Bh0, acc, 0, 0, 0);
        acc = __builtin_amdgcn_mfma_f32_16x16x32_bf16(Ah[1], Bl1, acc, 0, 0, 0);
        acc = __builtin_amdgcn_mfma_f32_16x16x32_bf16(Al[1], Bh1, acc, 0, 0, 0);
        // lo*lo terms ~2^-32 relative: negligible, dropped
#pragma unroll
        for (int e = 0; e < 4; ++e) {
            float sc = fmaf(-2.f, acc[e], nev);   // ||e||^2 - 2 x.e
            bool lt = sc < m1[e];                 // strict: ties keep lowest code
            i1[e] = lt ? code : i1[e];
            m1[e] = lt ? sc : m1[e];
        }
    }

    // argmin across the 16 lanes (same q) holding this row's columns
#pragma unroll
    for (int e = 0; e < 4; ++e) {
        float a1 = m1[e]; int ai = i1[e];
#pragma unroll
        for (int off = 1; off < 16; off <<= 1) {
            float o1 = __shfl_xor(a1, off);
            int   oi = __shfl_xor(ai, off);
            bool tk = (o1 < a1) || (o1 == a1 && oi < ai);  // tie -> lower index
            a1 = tk ? o1 : a1; ai = tk ? oi : ai;
        }
        if (col == 0) { smin[w][q * 4 + e] = a1; smid[w][q * 4 + e] = ai; }
    }
    __syncthreads();

    // combine the 4 waves' ct-quarters (wave order = ascending code blocks;
    // strict < keeps the earlier/lower code on ties)
    if (tid < 16) {
        float a1 = smin[0][tid]; int ai = smid[0][tid];
#pragma unroll
        for (int w2 = 1; w2 < 4; ++w2) {
            float o1 = smin[w2][tid]; int oi = smid[w2][tid];
            bool tk = (o1 < a1);
            a1 = tk ? o1 : a1; ai = tk ? oi : ai;
        }
        sidx[tid] = ai;
    }
    __syncthreads();

    // --- one-hot: 16 rows x 2 KB; one full row per iteration (coalesced) ----
#pragma unroll 4
    for (int i = 0; i < 16; ++i) {
        int c = i * 256 + tid;                 // chunk id: row*256 + k2
        int row = c >> 8, k2 = c & 255;
        int id = sidx[row];                    // uniform LDS read -> broadcast
        f32x2 v;
        v[0] = (id == k2 * 2)     ? 1.f : 0.f;
        v[1] = (id == k2 * 2 + 1) ? 1.f : 0.f;
        enc2[(size_t)(n0 + row) * 256 + k2] = v;
    }

    // --- quantized + loss: r = row (16), dg = dim-group (4 dims each) -------
    int r = tid & 15, dg = tid >> 4;
    int idq = sidx[r];
    float4 qv = *(const float4*)(cb + (size_t)idq * 64 + dg * 4);
    float qe[4] = {qv.x, qv.y, qv.z, qv.w};
    float* qp = out + 1 + (size_t)b * D_ * T_ + (size_t)(dg * 4) * T_ + t0 + r;

    float lsum = 0.f;
#pragma unroll
    for (int e = 0; e < 4; ++e) {
        float xv = X[dg * 4 + e][r];
        float diff = qe[e] - xv;
        lsum = fmaf(diff, diff, lsum);
        qp[(size_t)e * T_] = xv + diff;        // straight-through: x + (q - x)
    }
    if (tid < 16) atomicAdd(&hist[sidx[tid]], 1);  // one count per row (cheap: R0)

#pragma unroll
    for (int off = 32; off > 0; off >>= 1) lsum += __shfl_down(lsum, off);
    __shared__ float wsum[4];
    if ((tid & 63) == 0) wsum[tid >> 6] = lsum;
    __syncthreads();
    if (tid == 0) {
        double s = (double)wsum[0] + (double)wsum[1] + (double)wsum[2] + (double)wsum[3];
        atomicAdd(loss, s);
    }
}

// ---------------- K6: finalize loss + perplexity (trivial) ------------------
__global__ __launch_bounds__(512) void k6_final(const int* __restrict__ hist,
                                                const double* __restrict__ loss,
                                                float* __restrict__ out) {
    __shared__ double sh[512];
    int k = threadIdx.x;
    double p = (double)hist[k] / (double)N_;
    sh[k] = p * log(p + 1e-10);
    __syncthreads();
    for (int s = 256; s > 0; s >>= 1) {
        if (k < s) sh[k] += sh[k + s];
        __syncthreads();
    }
    if (k == 0) {
        out[1 + Q_] = (float)exp(-sh[0]);
        out[0] = (float)(1.25 * (*loss) / (double)Q_);
    }
}

extern "C" void kernel_launch(void* const* d_in, const int* in_sizes, int n_in,
                              void* d_out, int out_size, void* d_ws, size_t ws_size,
                              hipStream_t stream) {
    const float* in = (const float*)d_in[0];   // [16, 64, 4096] fp32
    const float* cb = (const float*)d_in[1];   // [512, 64] fp32
    float* out = (float*)d_out;
    char* ws = (char*)d_ws;

    double* loss  = (double*)(ws + WS_LOSS);
    int* hist     = (int*)(ws + WS_HIST);
    float* ne     = (float*)(ws + WS_NE);
    bf16x8* cbh   = (bf16x8*)(ws + WS_CBH);
    bf16x8* cbl   = (bf16x8*)(ws + WS_CBL);

    f32x2* enc2 = (f32x2*)(out + ENC_OFF);

    k0_init<<<16, 256, 0, stream>>>(cb, ne, hist, loss, cbh, cbl);
    k_main<<<N_ / 16, 256, 0, stream>>>(in, cb, cbh, cbl, ne, out, enc2, hist, loss);
    k6_final<<<1, 512, 0, stream>>>(hist, loss, out);
}

// Round 9
// 218.495 us; speedup vs baseline: 1.0376x; 1.0376x over previous
//
#include <hip/hip_runtime.h>

#define B_ 16
#define D_ 64
#define T_ 4096
#define K_ 512
#define N_ (B_*T_)        // 65536 vectors
#define Q_ (B_*D_*T_)     // 4194304 quantized elements
#define ENC_OFF ((size_t)(2 + Q_))  // encodings start in d_out
#define NK_ ((size_t)N_ * K_)       // 33554432 encoding floats

// ws layout (bytes) — ~136 KB (R0 layout)
#define WS_LOSS    0        // double
#define WS_HIST    16       // int[512]
#define WS_NE      2064     // float[512]
#define WS_CBH     4608     // bf16x8[32*2*64]  (64 KB) codebook hi frags
#define WS_CBL     70144    // bf16x8[32*2*64]  (64 KB) codebook lo frags

typedef __bf16 bf16x8 __attribute__((ext_vector_type(8)));
typedef float  f32x4  __attribute__((ext_vector_type(4)));

// ---------------- K0: init + ne + codebook hi/lo B-fragments ----------------
// Grid = 16 blocks x 256 threads.
__global__ __launch_bounds__(256) void k0_init(const float* __restrict__ cb,
                                               float* __restrict__ ne,
                                               int* __restrict__ hist,
                                               double* __restrict__ loss,
                                               bf16x8* __restrict__ cbh,
                                               bf16x8* __restrict__ cbl) {
    int bidx = blockIdx.x, tid = threadIdx.x;

    // ne: 32 codes per block, 8 lanes per code
    {
        int code = bidx * 32 + (tid >> 3), sl = tid & 7;
        float s = 0.f;
#pragma unroll
        for (int j = 0; j < 8; ++j) { float c = cb[code * 64 + sl * 8 + j]; s = fmaf(c, c, s); }
        s += __shfl_xor(s, 1); s += __shfl_xor(s, 2); s += __shfl_xor(s, 4);
        if (sl == 0) ne[code] = s;
    }
    if (bidx == 0) {
        hist[tid] = 0; hist[tid + 256] = 0;
        if (tid == 0) *loss = 0.0;
    }

    // B-frag element (ct,ks,lane,j) = cb[ct*16 + (lane&15)][ks*32 + (lane>>4)*8 + j]
    int e = bidx * 256 + tid;
    int ct = e >> 7, ks = (e >> 6) & 1, lane = e & 63;
    int code  = ct * 16 + (lane & 15);
    int dbase = ks * 32 + ((lane >> 4) << 3);
    bf16x8 h, l;
#pragma unroll
    for (int j = 0; j < 8; ++j) {
        float v = cb[code * 64 + dbase + j];
        __bf16 hv = (__bf16)v;
        __bf16 lv = (__bf16)(v - (float)hv);
        h[j] = hv; l[j] = lv;
    }
    cbh[(ct * 2 + ks) * 64 + lane] = h;
    cbl[(ct * 2 + ks) * 64 + lane] = l;
}

// ---------------- KZ: zero the encodings region — a fill clone --------------
// The harness fill writes this same buffer at 6.8 TB/s with wide stores.
// Structure identically: dependency-free grid-stride f32x4 streaming stores.
// enc base is only 8B-aligned ((2+Q_)%4==2), so x4-store the 16B-aligned
// interior [ENC_OFF+2, ENC_OFF+NK_-2) and patch the 2+2 edge floats.
__global__ __launch_bounds__(256) void k_zero(float* __restrict__ out) {
    f32x4* p4 = (f32x4*)(out + ENC_OFF + 2);       // 16B-aligned
    const size_t n4 = (NK_ - 4) / 4;               // 8388607 chunks
    f32x4 z = {0.f, 0.f, 0.f, 0.f};
    size_t stride = (size_t)gridDim.x * 256;
    for (size_t c = (size_t)blockIdx.x * 256 + threadIdx.x; c < n4; c += stride)
        p4[c] = z;
    if (blockIdx.x == 0 && threadIdx.x == 0) {
        out[ENC_OFF] = 0.f;           out[ENC_OFF + 1] = 0.f;
        out[ENC_OFF + NK_ - 2] = 0.f; out[ENC_OFF + NK_ - 1] = 0.f;
    }
}

// ---------------- KA: stage + MFMA argmin + quant + loss (R0 loop, no enc) --
// Block = 256 thr = 4 waves = 64 rows; grid = 1024 (R0's measured-best
// structure). The 64-iteration one-hot loop is DELETED — kZ pre-zeroed the
// enc region; each row writes only its single 1.0 (stream-ordered after kZ).
__global__ __launch_bounds__(256) void k_argmin(const float* __restrict__ in,
                                                const float* __restrict__ cb,
                                                const bf16x8* __restrict__ cbh,
                                                const bf16x8* __restrict__ cbl,
                                                const float* __restrict__ ne,
                                                float* __restrict__ out,
                                                int* __restrict__ hist,
                                                double* __restrict__ loss) {
    __shared__ float X[64][65];      // 16.6 KB; all access patterns <=2-way alias (free)
    __shared__ float ne_s[512];
    __shared__ int   sidx[64];
    int tid = threadIdx.x;
    int n0 = blockIdx.x * 64;
    int b  = n0 >> 12, t0 = n0 & (T_ - 1);

    { // stage x-tile: 4096 floats, 16 per thread, coalesced (R0 pattern)
        int tl = tid & 63, dg = tid >> 6;
#pragma unroll
        for (int i = 0; i < 16; ++i) {
            int d = dg * 16 + i;
            X[d][tl] = in[((size_t)b * 64 + d) * T_ + t0 + tl];
        }
    }
    ne_s[tid] = ne[tid];
    ne_s[tid + 256] = ne[tid + 256];
    __syncthreads();

    int w = tid >> 6, lane = tid & 63;
    int col = lane & 15, q = lane >> 4;

    // A-frags: wave w owns row-tile w. A[m][k=ks*32+q*8+j] = x_row[d]
    bf16x8 Ah[2], Al[2];
#pragma unroll
    for (int ks = 0; ks < 2; ++ks) {
        bf16x8 h, l;
#pragma unroll
        for (int j = 0; j < 8; ++j) {
            float v = X[ks * 32 + q * 8 + j][w * 16 + col];
            __bf16 hv = (__bf16)v;
            __bf16 lv = (__bf16)(v - (float)hv);
            h[j] = hv; l[j] = lv;
        }
        Ah[ks] = h; Al[ks] = l;
    }

    float m1[4]; int i1[4];
#pragma unroll
    for (int e = 0; e < 4; ++e) { m1[e] = 3.4e38f; i1[e] = 0; }

    for (int ct = 0; ct < 32; ++ct) {
        bf16x8 Bh0 = cbh[(ct * 2 + 0) * 64 + lane];
        bf16x8 Bh1 = cbh[(ct * 2 + 1) * 64 + lane];
        bf16x8 Bl0 = cbl[(ct * 2 + 0) * 64 + lane];
        bf16x8 Bl1 = cbl[(ct * 2 + 1) * 64 + lane];
        float nev = ne_s[ct * 16 + col];
        int code = ct * 16 + col;
        f32x4 acc = {0.f, 0.f, 0.f, 0.f};
        acc = __builtin_amdgcn_mfma_f32_16x16x32_bf16(Ah[0], Bh0, acc, 0, 0, 0);
        acc = __builtin_amdgcn_mfma_f32_16x16x32_bf16(Ah[1], Bh1, acc, 0, 0, 0);
        acc = __builtin_amdgcn_mfma_f32_16x16x32_bf16(Ah[0], Bl0, acc, 0, 0, 0);
        acc = __builtin_amdgcn_mfma_f32_16x16x32_bf16(Al[0], Bh0, acc, 0, 0, 0);
        acc = __builtin_amdgcn_mfma_f32_16x16x32_bf16(Ah[1], Bl1, acc, 0, 0, 0);
        acc = __builtin_amdgcn_mfma_f32_16x16x32_bf16(Al[1], Bh1, acc, 0, 0, 0);
        // lo*lo terms ~2^-32 relative: negligible, dropped
#pragma unroll
        for (int e = 0; e < 4; ++e) {
            float sc = fmaf(-2.f, acc[e], nev);   // ||e||^2 - 2 x.e
            bool lt = sc < m1[e];
            i1[e] = lt ? code : i1[e];
            m1[e] = lt ? sc : m1[e];
        }
    }

    // argmin across the 16 lanes (same q) holding this row's columns
#pragma unroll
    for (int e = 0; e < 4; ++e) {
        float a1 = m1[e]; int ai = i1[e];
#pragma unroll
        for (int off = 1; off < 16; off <<= 1) {
            float o1 = __shfl_xor(a1, off);
            int   oi = __shfl_xor(ai, off);
            bool tk = (o1 < a1) || (o1 == a1 && oi < ai);  // tie -> lower index
            a1 = tk ? o1 : a1; ai = tk ? oi : ai;
        }
        if (col == 0) sidx[w * 16 + q * 4 + e] = ai;
    }
    __syncthreads();

    // --- quantized + loss: lane = row, 16 dims per thread (R0 pattern) ------
    int tl = tid & 63, dg = tid >> 6;
    int idq = sidx[tl];
    const float4* cq4 = (const float4*)(cb + (size_t)idq * 64 + dg * 16);
    float* qp = out + 1 + (size_t)b * D_ * T_ + (size_t)(dg * 16) * T_ + t0 + tl;

    float lsum = 0.f;
#pragma unroll
    for (int j4 = 0; j4 < 4; ++j4) {
        float4 qv = cq4[j4];
        float qe[4] = {qv.x, qv.y, qv.z, qv.w};
#pragma unroll
        for (int e = 0; e < 4; ++e) {
            int dl = j4 * 4 + e;               // 0..15
            float xv = X[dg * 16 + dl][tl];
            float diff = qe[e] - xv;
            lsum = fmaf(diff, diff, lsum);
            qp[(size_t)dl * T_] = xv + diff;   // straight-through: x + (q - x)
        }
    }
    if (tid < 64) {
        int id = sidx[tid];
        // single 4B store of this row's one-hot 1.0 (zeros pre-written by kZ)
        out[ENC_OFF + (size_t)(n0 + tid) * K_ + id] = 1.0f;
        atomicAdd(&hist[id], 1);               // device scope, proven cheap (R0)
    }

#pragma unroll
    for (int off = 32; off > 0; off >>= 1) lsum += __shfl_down(lsum, off);
    __shared__ float wsum[4];
    if ((tid & 63) == 0) wsum[tid >> 6] = lsum;
    __syncthreads();
    if (tid == 0) {
        double s = (double)wsum[0] + (double)wsum[1] + (double)wsum[2] + (double)wsum[3];
        atomicAdd(loss, s);
    }
}

// ---------------- K6: finalize loss + perplexity (trivial) ------------------
__global__ __launch_bounds__(512) void k6_final(const int* __restrict__ hist,
                                                const double* __restrict__ loss,
                                                float* __restrict__ out) {
    __shared__ double sh[512];
    int k = threadIdx.x;
    double p = (double)hist[k] / (double)N_;
    sh[k] = p * log(p + 1e-10);
    __syncthreads();
    for (int s = 256; s > 0; s >>= 1) {
        if (k < s) sh[k] += sh[k + s];
        __syncthreads();
    }
    if (k == 0) {
        out[1 + Q_] = (float)exp(-sh[0]);
        out[0] = (float)(1.25 * (*loss) / (double)Q_);
    }
}

extern "C" void kernel_launch(void* const* d_in, const int* in_sizes, int n_in,
                              void* d_out, int out_size, void* d_ws, size_t ws_size,
                              hipStream_t stream) {
    const float* in = (const float*)d_in[0];   // [16, 64, 4096] fp32
    const float* cb = (const float*)d_in[1];   // [512, 64] fp32
    float* out = (float*)d_out;
    char* ws = (char*)d_ws;

    double* loss  = (double*)(ws + WS_LOSS);
    int* hist     = (int*)(ws + WS_HIST);
    float* ne     = (float*)(ws + WS_NE);
    bf16x8* cbh   = (bf16x8*)(ws + WS_CBH);
    bf16x8* cbl   = (bf16x8*)(ws + WS_CBL);

    k0_init<<<16, 256, 0, stream>>>(cb, ne, hist, loss, cbh, cbl);
    k_zero<<<2048, 256, 0, stream>>>(out);
    k_argmin<<<N_ / 64, 256, 0, stream>>>(in, cb, cbh, cbl, ne, out, hist, loss);
    k6_final<<<1, 512, 0, stream>>>(hist, loss, out);
}